// Round 3
// baseline (240.946 us; speedup 1.0000x reference)
//
#include <hip/hip_runtime.h>

#define NN 50000
#define NE 800000
#define ALPHA 0.2f
#define BCAP 64

typedef unsigned int u32;
typedef unsigned short u16t;

// ---- K0: transpose W [128][256] fp32 into Wt[k][f'] (f'<128: Hs half W[f'][k];
// f'>=128: Hd half W[f'-128][128+k]) ----
__global__ void k_wt(const float* __restrict__ W, float* __restrict__ Wt) {
    int flat = blockIdx.x * 256 + threadIdx.x;      // 0..32767
    float v = W[flat];
    int r = flat >> 8;                              // W row f (0..127)
    int c = flat & 255;                             // col (0..255)
    int k  = c & 127;
    int fp = (c < 128) ? r : r + 128;
    Wt[k * 256 + fp] = v;
}

// ---- K1: node GEMM + score dots. 32 nodes/block, 256 threads (4 waves),
// wave w handles nodes node0+w*8 .. +7; lane fg computes f' = fg*4..fg*4+3. ----
__global__ __launch_bounds__(256) void k_gemm(
        const float* __restrict__ X, const float* __restrict__ Wt,
        const float* __restrict__ A,
        float* __restrict__ Hs, float* __restrict__ Hd,
        float* __restrict__ s1, float* __restrict__ s2) {
    __shared__ float xs[32 * 128];                  // 16 KB
    const int tid = threadIdx.x;
    const int node0 = blockIdx.x * 32;

    // stage up to 32 input rows (fp32), zero-fill past NN
    {
        const float4* Xg = (const float4*)X + (size_t)node0 * 32;
#pragma unroll
        for (int it = 0; it < 4; ++it) {
            int flat = it * 256 + tid;              // 0..1023 float4s
            int row = flat >> 5;
            float4 v = make_float4(0.f, 0.f, 0.f, 0.f);
            if (node0 + row < NN) v = Xg[flat];
            ((float4*)xs)[flat] = v;
        }
    }
    __syncthreads();

    const int fg = tid & 63;
    const int f0 = fg * 4;
    const int nbase = (tid >> 6) * 8;               // wave's first node (in-block)

    float acc[8][4];
#pragma unroll
    for (int a_ = 0; a_ < 8; ++a_)
#pragma unroll
        for (int b_ = 0; b_ < 4; ++b_) acc[a_][b_] = 0.f;

    const float4* Wt4 = (const float4*)Wt;
    for (int k = 0; k < 128; ++k) {
        float4 w = Wt4[k * 64 + fg];                // coalesced, 256KB L2-resident
#pragma unroll
        for (int nn = 0; nn < 8; ++nn) {
            float x = xs[(nbase + nn) * 128 + k];   // LDS broadcast
            acc[nn][0] += x * w.x;
            acc[nn][1] += x * w.y;
            acc[nn][2] += x * w.z;
            acc[nn][3] += x * w.w;
        }
    }

    float av0 = A[f0 & 127], av1 = A[(f0 + 1) & 127],
          av2 = A[(f0 + 2) & 127], av3 = A[(f0 + 3) & 127];

#pragma unroll
    for (int nn = 0; nn < 8; ++nn) {
        int node = node0 + nbase + nn;
        float sp = acc[nn][0] * av0 + acc[nn][1] * av1 +
                   acc[nn][2] * av2 + acc[nn][3] * av3;
        sp += __shfl_xor(sp, 1);
        sp += __shfl_xor(sp, 2);
        sp += __shfl_xor(sp, 4);
        sp += __shfl_xor(sp, 8);
        sp += __shfl_xor(sp, 16);   // halves (lanes 0-31 / 32-63) never mix
        if (node < NN) {
            if (fg == 0)  s1[node] = sp;
            if (fg == 32) s2[node] = sp;
            if (f0 < 128) {
                *(float4*)&Hs[(size_t)node * 128 + f0] =
                    make_float4(acc[nn][0], acc[nn][1], acc[nn][2], acc[nn][3]);
            } else {
                *(float4*)&Hd[(size_t)node * 128 + (f0 - 128)] =
                    make_float4(acc[nn][0], acc[nn][1], acc[nn][2], acc[nn][3]);
            }
        }
    }
}

// ---- K2: counting-sort edges; bucket stores dst as u16 (NN < 65536) ----
__global__ void k_bucket(const int* __restrict__ srcArr,
                         const int* __restrict__ dstArr,
                         int* __restrict__ cnt, u16t* __restrict__ bucket) {
    int e = blockIdx.x * 256 + threadIdx.x;
    if (e < NE) {
        int s = srcArr[e];
        int d = dstArr[e];
        if (s < 0 || s >= NN) return;
        int slot = atomicAdd(&cnt[s], 1);
        if (slot < BCAP)
            bucket[(size_t)s * BCAP + slot] = (u16t)d;
    }
}

// ---- K3: per-node aggregation + denominator + ELU ----
__global__ __launch_bounds__(128) void k_agg(
        const int* __restrict__ cnt, const u16t* __restrict__ bucket,
        const float* __restrict__ s1, const float* __restrict__ s2,
        const float* __restrict__ Hs, const float* __restrict__ Hd,
        float* __restrict__ out) {
    __shared__ float wbuf[BCAP];
    __shared__ int   dbuf[BCAP];
    const int i = blockIdx.x;
    const int tid = threadIdx.x;               // feature index 0..127
    int deg = cnt[i];
    deg = (deg < 0) ? 0 : ((deg > BCAP) ? BCAP : deg);
    if (tid < BCAP) { wbuf[tid] = 0.f; dbuf[tid] = 0; }
    __syncthreads();
    float mys1 = s1[i];
    if (tid < deg) {
        int d = (int)bucket[(size_t)i * BCAP + tid];
        if (d >= NN) d = 0;
        float sc = mys1 + s2[d];
        sc = fminf(fmaxf(sc, -80.f), 80.f);
        float lr = fmaxf(sc, ALPHA * sc);      // leaky_relu
        wbuf[tid] = __expf(-lr);
        dbuf[tid] = d;
    }
    __syncthreads();

    float accv = 0.f, S = 0.f;
    int j = 0;
    for (; j + 3 < deg; j += 4) {
        float w0 = wbuf[j],   w1 = wbuf[j+1], w2 = wbuf[j+2], w3 = wbuf[j+3];
        int   d0 = dbuf[j],   d1 = dbuf[j+1], d2 = dbuf[j+2], d3 = dbuf[j+3];
        float h0 = Hd[(size_t)d0 * 128 + tid];
        float h1 = Hd[(size_t)d1 * 128 + tid];
        float h2 = Hd[(size_t)d2 * 128 + tid];
        float h3 = Hd[(size_t)d3 * 128 + tid];
        accv += w0 * h0 + w1 * h1 + w2 * h2 + w3 * h3;
        S += w0 + w1 + w2 + w3;
    }
    for (; j < deg; ++j) {
        float w = wbuf[j];
        int d = dbuf[j];
        accv += w * Hd[(size_t)d * 128 + tid];
        S += w;
    }
    S = fmaxf(S, 1e-12f);

    float h = (deg == 0) ? 0.f : (Hs[(size_t)i * 128 + tid] + accv / S);
    float o = (h > 0.f) ? h : (__expf(h) - 1.f);   // ELU alpha=1
    out[(size_t)i * 128 + tid] = o;
}

extern "C" void kernel_launch(void* const* d_in, const int* in_sizes, int n_in,
                              void* d_out, int out_size, void* d_ws, size_t ws_size,
                              hipStream_t stream) {
    const float* X = (const float*)d_in[0];    // input_ fp32 [NN][128]
    const float* W = (const float*)d_in[1];    // W fp32 [128][256]
    const float* A = (const float*)d_in[2];    // a fp32 [1][128]
    const int* edge = (const int*)d_in[3];     // [2][NE] int32
    const int* srcArr = edge;
    const int* dstArr = edge + NE;
    float* out = (float*)d_out;

    char* ws = (char*)d_ws;
    size_t off = 0;
    auto alloc = [&](size_t bytes) {
        void* p = ws + off;
        off = (off + bytes + 255) & ~(size_t)255;
        return p;
    };
    float* Hs  = (float*)alloc((size_t)NN * 128 * 4);   // 25.6 MB
    float* Hd  = (float*)alloc((size_t)NN * 128 * 4);   // 25.6 MB
    float* s1  = (float*)alloc((size_t)NN * 4);
    float* s2  = (float*)alloc((size_t)NN * 4);
    int*   cnt = (int*)alloc((size_t)NN * 4);
    u16t*  bkt = (u16t*)alloc((size_t)NN * BCAP * 2);   // 6.4 MB
    float* Wt  = (float*)alloc(256 * 256 * 4);          // 256 KB
    (void)ws_size; (void)in_sizes; (void)n_in; (void)out_size;

    hipMemsetAsync(cnt, 0, (size_t)NN * 4, stream);
    k_wt<<<128, 256, 0, stream>>>(W, Wt);
    k_gemm<<<(NN + 31) / 32, 256, 0, stream>>>(X, Wt, A, Hs, Hd, s1, s2);
    k_bucket<<<NE / 256, 256, 0, stream>>>(srcArr, dstArr, cnt, bkt);
    k_agg<<<NN, 128, 0, stream>>>(cnt, bkt, s1, s2, Hs, Hd, out);
}

// Round 4
// 216.977 us; speedup vs baseline: 1.1105x; 1.1105x over previous
//
#include <hip/hip_runtime.h>

#define NN 50000
#define NE 800000
#define ALPHA 0.2f
#define BCAP 64

typedef unsigned int u32;
typedef unsigned short u16t;

using frag  = __attribute__((ext_vector_type(8))) short;  // 8 bf16 (4 VGPRs)
using f32x4 = __attribute__((ext_vector_type(4))) float;  // 4 fp32

__device__ __forceinline__ float bf2f(u16t v) { return __uint_as_float(((u32)v) << 16); }
__device__ __forceinline__ u16t f2bf(float f) {
    u32 x = __float_as_uint(f);
    u32 r = x + 0x7fffu + ((x >> 16) & 1u);   // RNE; finite inputs
    return (u16t)(r >> 16);
}

// ---- K0: pack W [128][256] fp32 into Wb[n][k] bf16 (B-operand-friendly):
// n<128: Wb[n][k] = W[n][k]   (Hs half);  n>=128: Wb[n][k] = W[n-128][128+k]
__global__ void k_wb(const float* __restrict__ W, u16t* __restrict__ Wb) {
    int flat = blockIdx.x * 256 + threadIdx.x;   // 0..32767
    int n = flat >> 7, k = flat & 127;
    float v = (n < 128) ? W[n * 256 + k] : W[(n - 128) * 256 + 128 + k];
    Wb[flat] = f2bf(v);
}

// ---- K1: MFMA node GEMM + fused score dots.
// 4 waves/block; wave owns m-tile of 16 nodes x all 256 output cols.
// 50000/16 = 3125 m-tiles exactly; grid 782 blocks (last 3 waves idle).
__global__ __launch_bounds__(256) void k_gemm(
        const float* __restrict__ X, const u16t* __restrict__ Wb,
        const float* __restrict__ A,
        float* __restrict__ Hs, u16t* __restrict__ Hd,
        float* __restrict__ s1, float* __restrict__ s2) {
    const int tid  = threadIdx.x;
    const int wave = tid >> 6;
    const int lane = tid & 63;
    const int mt   = blockIdx.x * 4 + wave;
    if (mt >= 3125) return;                      // no LDS/barriers -> safe early exit
    const int col  = lane & 15;                  // C col selector / A row selector
    const int quad = lane >> 4;                  // 0..3
    const int node0 = mt * 16;

    // A-frags: lane holds X[node0+col][ks*32 + quad*8 + j], j=0..7 (fp32->bf16)
    frag afrag[4];
    const float* xrow = X + (size_t)(node0 + col) * 128;
#pragma unroll
    for (int ks = 0; ks < 4; ++ks) {
        const float4* p = (const float4*)(xrow + ks * 32 + quad * 8);
        float4 v0 = p[0], v1 = p[1];
        frag a;
        a[0] = (short)f2bf(v0.x); a[1] = (short)f2bf(v0.y);
        a[2] = (short)f2bf(v0.z); a[3] = (short)f2bf(v0.w);
        a[4] = (short)f2bf(v1.x); a[5] = (short)f2bf(v1.y);
        a[6] = (short)f2bf(v1.z); a[7] = (short)f2bf(v1.w);
        afrag[ks] = a;
    }

    f32x4 acc[16];
#pragma unroll
    for (int nt = 0; nt < 16; ++nt)
#pragma unroll
        for (int r = 0; r < 4; ++r) acc[nt][r] = 0.f;

    // B-frags straight from global (Wb is 64KB, L2-resident, broadcast-read):
    // lane needs Wb[nt*16+col][ks*32 + quad*8 + j] -> frag index (n*128 + ks*32+quad*8)/8
    const frag* WbF = (const frag*)Wb;
#pragma unroll
    for (int nt = 0; nt < 16; ++nt) {
        const int n = nt * 16 + col;
#pragma unroll
        for (int ks = 0; ks < 4; ++ks) {
            frag b = WbF[n * 16 + ks * 4 + quad];
            acc[nt] = __builtin_amdgcn_mfma_f32_16x16x32_bf16(afrag[ks], b, acc[nt], 0, 0, 0);
        }
    }

    // a-vector values for this lane's columns (f = (nt&7)*16 + col)
    float a_n[16];
#pragma unroll
    for (int nt = 0; nt < 16; ++nt) a_n[nt] = A[(nt * 16 + col) & 127];

    // fused score reduction: row m = node0 + quad*4 + r; reduce over 16 lanes of the quad
#pragma unroll
    for (int r = 0; r < 4; ++r) {
        float p1 = 0.f, p2 = 0.f;
#pragma unroll
        for (int nt = 0; nt < 8; ++nt)  p1 += acc[nt][r] * a_n[nt];
#pragma unroll
        for (int nt = 8; nt < 16; ++nt) p2 += acc[nt][r] * a_n[nt];
        p1 += __shfl_xor(p1, 1); p1 += __shfl_xor(p1, 2);
        p1 += __shfl_xor(p1, 4); p1 += __shfl_xor(p1, 8);
        p2 += __shfl_xor(p2, 1); p2 += __shfl_xor(p2, 2);
        p2 += __shfl_xor(p2, 4); p2 += __shfl_xor(p2, 8);
        if (col == 0) {
            int node = node0 + quad * 4 + r;
            s1[node] = p1;
            s2[node] = p2;
        }
    }

    // stores: C/D layout col=lane&15, row=quad*4+reg
#pragma unroll
    for (int nt = 0; nt < 8; ++nt)
#pragma unroll
        for (int r = 0; r < 4; ++r)
            Hs[(size_t)(node0 + quad * 4 + r) * 128 + nt * 16 + col] = acc[nt][r];
#pragma unroll
    for (int nt = 8; nt < 16; ++nt)
#pragma unroll
        for (int r = 0; r < 4; ++r)
            Hd[(size_t)(node0 + quad * 4 + r) * 128 + (nt - 8) * 16 + col] = f2bf(acc[nt][r]);
}

// ---- K2: counting-sort edges; bucket stores dst as u16 (NN < 65536) ----
__global__ void k_bucket(const int* __restrict__ srcArr,
                         const int* __restrict__ dstArr,
                         int* __restrict__ cnt, u16t* __restrict__ bucket) {
    int e = blockIdx.x * 256 + threadIdx.x;
    if (e < NE) {
        int s = srcArr[e];
        int d = dstArr[e];
        if (s < 0 || s >= NN) return;
        int slot = atomicAdd(&cnt[s], 1);
        if (slot < BCAP)
            bucket[(size_t)s * BCAP + slot] = (u16t)d;
    }
}

// ---- K3: per-node aggregation + denominator + ELU (Hd now bf16) ----
__global__ __launch_bounds__(128) void k_agg(
        const int* __restrict__ cnt, const u16t* __restrict__ bucket,
        const float* __restrict__ s1, const float* __restrict__ s2,
        const float* __restrict__ Hs, const u16t* __restrict__ Hd,
        float* __restrict__ out) {
    __shared__ float wbuf[BCAP];
    __shared__ int   dbuf[BCAP];
    const int i = blockIdx.x;
    const int tid = threadIdx.x;               // feature index 0..127
    int deg = cnt[i];
    deg = (deg < 0) ? 0 : ((deg > BCAP) ? BCAP : deg);
    if (tid < BCAP) { wbuf[tid] = 0.f; dbuf[tid] = 0; }
    __syncthreads();
    float mys1 = s1[i];
    if (tid < deg) {
        int d = (int)bucket[(size_t)i * BCAP + tid];
        if (d >= NN) d = 0;
        float sc = mys1 + s2[d];
        sc = fminf(fmaxf(sc, -80.f), 80.f);
        float lr = fmaxf(sc, ALPHA * sc);      // leaky_relu
        wbuf[tid] = __expf(-lr);
        dbuf[tid] = d;
    }
    __syncthreads();

    float accv = 0.f, S = 0.f;
    int j = 0;
    for (; j + 3 < deg; j += 4) {
        float w0 = wbuf[j],   w1 = wbuf[j+1], w2 = wbuf[j+2], w3 = wbuf[j+3];
        int   d0 = dbuf[j],   d1 = dbuf[j+1], d2 = dbuf[j+2], d3 = dbuf[j+3];
        float h0 = bf2f(Hd[(size_t)d0 * 128 + tid]);
        float h1 = bf2f(Hd[(size_t)d1 * 128 + tid]);
        float h2 = bf2f(Hd[(size_t)d2 * 128 + tid]);
        float h3 = bf2f(Hd[(size_t)d3 * 128 + tid]);
        accv += w0 * h0 + w1 * h1 + w2 * h2 + w3 * h3;
        S += w0 + w1 + w2 + w3;
    }
    for (; j < deg; ++j) {
        float w = wbuf[j];
        int d = dbuf[j];
        accv += w * bf2f(Hd[(size_t)d * 128 + tid]);
        S += w;
    }
    S = fmaxf(S, 1e-12f);

    float h = (deg == 0) ? 0.f : (Hs[(size_t)i * 128 + tid] + accv / S);
    float o = (h > 0.f) ? h : (__expf(h) - 1.f);   // ELU alpha=1
    out[(size_t)i * 128 + tid] = o;
}

extern "C" void kernel_launch(void* const* d_in, const int* in_sizes, int n_in,
                              void* d_out, int out_size, void* d_ws, size_t ws_size,
                              hipStream_t stream) {
    const float* X = (const float*)d_in[0];    // input_ fp32 [NN][128]
    const float* W = (const float*)d_in[1];    // W fp32 [128][256]
    const float* A = (const float*)d_in[2];    // a fp32 [1][128]
    const int* edge = (const int*)d_in[3];     // [2][NE] int32
    const int* srcArr = edge;
    const int* dstArr = edge + NE;
    float* out = (float*)d_out;

    char* ws = (char*)d_ws;
    size_t off = 0;
    auto alloc = [&](size_t bytes) {
        void* p = ws + off;
        off = (off + bytes + 255) & ~(size_t)255;
        return p;
    };
    float* Hs  = (float*)alloc((size_t)NN * 128 * 4);   // 25.6 MB
    u16t*  Hd  = (u16t*)alloc((size_t)NN * 128 * 2);    // 12.8 MB
    float* s1  = (float*)alloc((size_t)NN * 4);
    float* s2  = (float*)alloc((size_t)NN * 4);
    int*   cnt = (int*)alloc((size_t)NN * 4);
    u16t*  bkt = (u16t*)alloc((size_t)NN * BCAP * 2);   // 6.4 MB
    u16t*  Wb  = (u16t*)alloc(256 * 128 * 2);           // 64 KB
    (void)ws_size; (void)in_sizes; (void)n_in; (void)out_size;

    hipMemsetAsync(cnt, 0, (size_t)NN * 4, stream);
    k_wb<<<128, 256, 0, stream>>>(W, Wb);
    k_gemm<<<782, 256, 0, stream>>>(X, Wb, A, Hs, Hd, s1, s2);
    k_bucket<<<NE / 256, 256, 0, stream>>>(srcArr, dstArr, cnt, bkt);
    k_agg<<<NN, 128, 0, stream>>>(cnt, bkt, s1, s2, Hs, Hd, out);
}

// Round 5
// 188.097 us; speedup vs baseline: 1.2810x; 1.1535x over previous
//
#include <hip/hip_runtime.h>

#define NN 50000
#define NE 800000
#define ALPHA 0.2f
#define BCAP 64

typedef unsigned int u32;
typedef unsigned short u16t;

using frag  = __attribute__((ext_vector_type(8))) short;  // 8 bf16 (4 VGPRs)
using f32x4 = __attribute__((ext_vector_type(4))) float;  // 4 fp32

__device__ __forceinline__ float bf2f(u16t v) { return __uint_as_float(((u32)v) << 16); }
__device__ __forceinline__ u16t f2bf(float f) {
    u32 x = __float_as_uint(f);
    u32 r = x + 0x7fffu + ((x >> 16) & 1u);   // RNE; finite inputs
    return (u16t)(r >> 16);
}

// ---- K0: pack W fp32 [128][256] into frag-sequential bf16 WbSeq + zero cnt.
// Element o = fid*8 + j, fid = nt*256/... : quad=fid&3, col=(fid>>2)&15,
// ks=(fid>>6)&3, nt=fid>>8; holds Wcat[f'=nt*16+col][k=ks*32+quad*8+j].
// This makes each wave's B-frag load for fixed (nt,ks) one contiguous 1KB burst.
__global__ void k_wb(const float* __restrict__ W, u16t* __restrict__ WbSeq,
                     int* __restrict__ cnt) {
    int o = blockIdx.x * 256 + threadIdx.x;        // 0..50175
    if (o < 32768) {
        int j = o & 7, fid = o >> 3;
        int quad = fid & 3, col = (fid >> 2) & 15, ks = (fid >> 6) & 3, nt = fid >> 8;
        int fp = nt * 16 + col;
        int k = ks * 32 + quad * 8 + j;
        float v = (fp < 128) ? W[fp * 256 + k] : W[(fp - 128) * 256 + 128 + k];
        WbSeq[o] = f2bf(v);
    }
    if (o < NN) cnt[o] = 0;
}

// ---- K1: MFMA node GEMM + fused score dots.
// 4 waves/block; wave owns one 16-node m-tile x all 256 cols. 3125 m-tiles.
__global__ __launch_bounds__(256) void k_gemm(
        const float* __restrict__ X, const u16t* __restrict__ WbSeq,
        const float* __restrict__ A,
        float* __restrict__ Hs, u16t* __restrict__ Hd,
        float* __restrict__ s1, float* __restrict__ s2) {
    const int tid  = threadIdx.x;
    const int wave = tid >> 6;
    const int lane = tid & 63;
    const int mt   = blockIdx.x * 4 + wave;
    if (mt >= 3125) return;                      // no LDS/barriers -> safe
    const int col  = lane & 15;
    const int quad = lane >> 4;
    const int node0 = mt * 16;
    const int laneoff = col * 4 + quad;          // frag-seq per-lane offset

    // A-frags: lane holds X[node0+col][ks*32 + quad*8 + j] (fp32 -> bf16)
    frag afrag[4];
    const float* xrow = X + (size_t)(node0 + col) * 128;
#pragma unroll
    for (int ks = 0; ks < 4; ++ks) {
        const float4* p = (const float4*)(xrow + ks * 32 + quad * 8);
        float4 v0 = p[0], v1 = p[1];
        frag a;
        a[0] = (short)f2bf(v0.x); a[1] = (short)f2bf(v0.y);
        a[2] = (short)f2bf(v0.z); a[3] = (short)f2bf(v0.w);
        a[4] = (short)f2bf(v1.x); a[5] = (short)f2bf(v1.y);
        a[6] = (short)f2bf(v1.z); a[7] = (short)f2bf(v1.w);
        afrag[ks] = a;
    }

    f32x4 acc[16];
#pragma unroll
    for (int nt = 0; nt < 16; ++nt)
#pragma unroll
        for (int r = 0; r < 4; ++r) acc[nt][r] = 0.f;

    // B-frags: coalesced 1KB bursts from L2-resident 64KB WbSeq
    const frag* WbF = (const frag*)WbSeq;
#pragma unroll
    for (int nt = 0; nt < 16; ++nt) {
#pragma unroll
        for (int ks = 0; ks < 4; ++ks) {
            frag b = WbF[nt * 256 + ks * 64 + laneoff];
            acc[nt] = __builtin_amdgcn_mfma_f32_16x16x32_bf16(afrag[ks], b, acc[nt], 0, 0, 0);
        }
    }

    // fused scores: row m = node0 + quad*4 + r, reduce over the quad's 16 lanes
#pragma unroll
    for (int r = 0; r < 4; ++r) {
        float p1 = 0.f, p2 = 0.f;
#pragma unroll
        for (int nt = 0; nt < 8; ++nt)  p1 += acc[nt][r] * A[nt * 16 + col];
#pragma unroll
        for (int nt = 8; nt < 16; ++nt) p2 += acc[nt][r] * A[(nt - 8) * 16 + col];
        p1 += __shfl_xor(p1, 1); p1 += __shfl_xor(p1, 2);
        p1 += __shfl_xor(p1, 4); p1 += __shfl_xor(p1, 8);
        p2 += __shfl_xor(p2, 1); p2 += __shfl_xor(p2, 2);
        p2 += __shfl_xor(p2, 4); p2 += __shfl_xor(p2, 8);
        if (col == 0) {
            int node = node0 + quad * 4 + r;
            s1[node] = p1;
            s2[node] = p2;
        }
    }

    // stores: C/D layout col=lane&15, row=quad*4+reg
#pragma unroll
    for (int nt = 0; nt < 8; ++nt)
#pragma unroll
        for (int r = 0; r < 4; ++r)
            Hs[(size_t)(node0 + quad * 4 + r) * 128 + nt * 16 + col] = acc[nt][r];
#pragma unroll
    for (int nt = 8; nt < 16; ++nt)
#pragma unroll
        for (int r = 0; r < 4; ++r)
            Hd[(size_t)(node0 + quad * 4 + r) * 128 + (nt - 8) * 16 + col] = f2bf(acc[nt][r]);
}

// ---- K2: counting-sort edges; bucket stores dst as u16 (NN < 65536) ----
__global__ void k_bucket(const int* __restrict__ srcArr,
                         const int* __restrict__ dstArr,
                         int* __restrict__ cnt, u16t* __restrict__ bucket) {
    int e = blockIdx.x * 256 + threadIdx.x;
    if (e < NE) {
        int s = srcArr[e];
        int d = dstArr[e];
        if (s < 0 || s >= NN) return;
        int slot = atomicAdd(&cnt[s], 1);
        if (slot < BCAP)
            bucket[(size_t)s * BCAP + slot] = (u16t)d;
    }
}

// ---- K3: one wave per node; uint4 gathers (4 edge-rows / instruction, 2-deep) ----
__global__ __launch_bounds__(256) void k_agg(
        const int* __restrict__ cnt, const u16t* __restrict__ bucket,
        const float* __restrict__ s1, const float* __restrict__ s2,
        const float* __restrict__ Hs, const u16t* __restrict__ Hd,
        float* __restrict__ out) {
    __shared__ float wls[4][BCAP];
    __shared__ int   dls[4][BCAP];
    const int wave = threadIdx.x >> 6;
    const int lane = threadIdx.x & 63;
    const int i = blockIdx.x * 4 + wave;           // node; grid 12500*4 = NN exact

    int deg = cnt[i];
    deg = (deg < 0) ? 0 : ((deg > BCAP) ? BCAP : deg);
    float w = 0.f; int dl = 0;
    if (lane < deg) {
        dl = (int)bucket[(size_t)i * BCAP + lane];
        if (dl >= NN) dl = 0;
        float sc = s1[i] + s2[dl];
        sc = fminf(fmaxf(sc, -80.f), 80.f);
        w = __expf(-fmaxf(sc, ALPHA * sc));        // exp(-leaky_relu(sc))
    }
    wls[wave][lane] = w;
    dls[wave][lane] = dl;
    float S = w;
    S += __shfl_xor(S, 1);  S += __shfl_xor(S, 2);  S += __shfl_xor(S, 4);
    S += __shfl_xor(S, 8);  S += __shfl_xor(S, 16); S += __shfl_xor(S, 32);
    __syncthreads();

    const int g  = lane >> 4;                      // which of 4 edges this lane serves
    const int fb = (lane & 15) * 8;                // feature base (8 bf16 = 16B)
    float acc[8];
#pragma unroll
    for (int k = 0; k < 8; ++k) acc[k] = 0.f;

    const int iters = (deg + 3) >> 2;
    int j = 0;
    for (; j + 1 < iters; j += 2) {                // 2 gathers in flight per lane
        int e0 = j * 4 + g, e1 = e0 + 4;           // <= 63 always (w=0 pads)
        float w0 = wls[wave][e0], w1 = wls[wave][e1];
        int   d0 = dls[wave][e0], d1 = dls[wave][e1];
        uint4 h0 = *(const uint4*)&Hd[(size_t)d0 * 128 + fb];
        uint4 h1 = *(const uint4*)&Hd[(size_t)d1 * 128 + fb];
        acc[0] += w0 * bf2f((u16t)(h0.x & 0xffff)); acc[1] += w0 * bf2f((u16t)(h0.x >> 16));
        acc[2] += w0 * bf2f((u16t)(h0.y & 0xffff)); acc[3] += w0 * bf2f((u16t)(h0.y >> 16));
        acc[4] += w0 * bf2f((u16t)(h0.z & 0xffff)); acc[5] += w0 * bf2f((u16t)(h0.z >> 16));
        acc[6] += w0 * bf2f((u16t)(h0.w & 0xffff)); acc[7] += w0 * bf2f((u16t)(h0.w >> 16));
        acc[0] += w1 * bf2f((u16t)(h1.x & 0xffff)); acc[1] += w1 * bf2f((u16t)(h1.x >> 16));
        acc[2] += w1 * bf2f((u16t)(h1.y & 0xffff)); acc[3] += w1 * bf2f((u16t)(h1.y >> 16));
        acc[4] += w1 * bf2f((u16t)(h1.z & 0xffff)); acc[5] += w1 * bf2f((u16t)(h1.z >> 16));
        acc[6] += w1 * bf2f((u16t)(h1.w & 0xffff)); acc[7] += w1 * bf2f((u16t)(h1.w >> 16));
    }
    if (j < iters) {
        int e0 = j * 4 + g;
        float w0 = wls[wave][e0];
        int   d0 = dls[wave][e0];
        uint4 h0 = *(const uint4*)&Hd[(size_t)d0 * 128 + fb];
        acc[0] += w0 * bf2f((u16t)(h0.x & 0xffff)); acc[1] += w0 * bf2f((u16t)(h0.x >> 16));
        acc[2] += w0 * bf2f((u16t)(h0.y & 0xffff)); acc[3] += w0 * bf2f((u16t)(h0.y >> 16));
        acc[4] += w0 * bf2f((u16t)(h0.z & 0xffff)); acc[5] += w0 * bf2f((u16t)(h0.z >> 16));
        acc[6] += w0 * bf2f((u16t)(h0.w & 0xffff)); acc[7] += w0 * bf2f((u16t)(h0.w >> 16));
    }

    // fold the 4 edge-groups (lane bits 4,5)
#pragma unroll
    for (int k = 0; k < 8; ++k) {
        acc[k] += __shfl_xor(acc[k], 16);
        acc[k] += __shfl_xor(acc[k], 32);
    }

    if (lane < 16) {
        float4 o0 = make_float4(0.f, 0.f, 0.f, 0.f), o1 = o0;
        if (deg > 0) {
            float inv = 1.f / fmaxf(S, 1e-12f);
            const float* hsrow = Hs + (size_t)i * 128 + fb;
            float4 hs0 = *(const float4*)hsrow;
            float4 hs1 = *(const float4*)(hsrow + 4);
            float h;
            h = hs0.x + acc[0] * inv; o0.x = (h > 0.f) ? h : (__expf(h) - 1.f);
            h = hs0.y + acc[1] * inv; o0.y = (h > 0.f) ? h : (__expf(h) - 1.f);
            h = hs0.z + acc[2] * inv; o0.z = (h > 0.f) ? h : (__expf(h) - 1.f);
            h = hs0.w + acc[3] * inv; o0.w = (h > 0.f) ? h : (__expf(h) - 1.f);
            h = hs1.x + acc[4] * inv; o1.x = (h > 0.f) ? h : (__expf(h) - 1.f);
            h = hs1.y + acc[5] * inv; o1.y = (h > 0.f) ? h : (__expf(h) - 1.f);
            h = hs1.z + acc[6] * inv; o1.z = (h > 0.f) ? h : (__expf(h) - 1.f);
            h = hs1.w + acc[7] * inv; o1.w = (h > 0.f) ? h : (__expf(h) - 1.f);
        }
        float* orow = out + (size_t)i * 128 + fb;
        *(float4*)orow = o0;
        *(float4*)(orow + 4) = o1;
    }
}

extern "C" void kernel_launch(void* const* d_in, const int* in_sizes, int n_in,
                              void* d_out, int out_size, void* d_ws, size_t ws_size,
                              hipStream_t stream) {
    const float* X = (const float*)d_in[0];    // input_ fp32 [NN][128]
    const float* W = (const float*)d_in[1];    // W fp32 [128][256]
    const float* A = (const float*)d_in[2];    // a fp32 [1][128]
    const int* edge = (const int*)d_in[3];     // [2][NE] int32
    const int* srcArr = edge;
    const int* dstArr = edge + NE;
    float* out = (float*)d_out;

    char* ws = (char*)d_ws;
    size_t off = 0;
    auto alloc = [&](size_t bytes) {
        void* p = ws + off;
        off = (off + bytes + 255) & ~(size_t)255;
        return p;
    };
    float* Hs  = (float*)alloc((size_t)NN * 128 * 4);   // 25.6 MB
    u16t*  Hd  = (u16t*)alloc((size_t)NN * 128 * 2);    // 12.8 MB
    float* s1  = (float*)alloc((size_t)NN * 4);
    float* s2  = (float*)alloc((size_t)NN * 4);
    int*   cnt = (int*)alloc((size_t)NN * 4);
    u16t*  bkt = (u16t*)alloc((size_t)NN * BCAP * 2);   // 6.4 MB
    u16t*  Wb  = (u16t*)alloc(256 * 128 * 2);           // 64 KB
    (void)ws_size; (void)in_sizes; (void)n_in; (void)out_size;

    k_wb<<<196, 256, 0, stream>>>(W, Wb, cnt);          // also zeroes cnt
    k_bucket<<<NE / 256, 256, 0, stream>>>(srcArr, dstArr, cnt, bkt);
    k_gemm<<<782, 256, 0, stream>>>(X, Wb, A, Hs, Hd, s1, s2);
    k_agg<<<NN / 4, 256, 0, stream>>>(cnt, bkt, s1, s2, Hs, Hd, out);
}